// Round 4
// baseline (226.064 us; speedup 1.0000x reference)
//
#include <hip/hip_runtime.h>
#include <math.h>

#define NB 8
#define SQ 1024
#define DM 1024
#define NH 16
#define NA 4
#define DKH 128

// ---- workspace layout (byte offsets, all 128B-aligned) ----
#define WS_XPART 0
#define WS_IDX   524288
#define WS_GATES 524416
#define WS_XB    524800
#define WS_WQT   (WS_XB  + 16777216)
#define WS_WKT   (WS_WQT + 4194304)
#define WS_WVT   (WS_WKT + 4194304)
#define WS_WOT   (WS_WVT + 4194304)
#define WS_Q     (WS_WOT + 1048576)
#define WS_K     (WS_Q  + 8388608)
#define WS_VT    (WS_K  + 8388608)
#define WS_CAT   (WS_VT + 8388608)
// total = WS_CAT + 8388608 = 64,487,936 bytes

typedef __attribute__((ext_vector_type(8))) short short8;
typedef __attribute__((ext_vector_type(4))) short short4v;
typedef __attribute__((ext_vector_type(4))) float f32x4;

#define MFMA16(a, b, c) __builtin_amdgcn_mfma_f32_16x16x32_bf16(a, b, c, 0, 0, 0)
#define GLL16(g, l) __builtin_amdgcn_global_load_lds( \
    (const __attribute__((address_space(1))) void*)(g), \
    (__attribute__((address_space(3))) void*)(l), 16, 0, 0)

__device__ __forceinline__ short f2bf(float f) {
  unsigned u = __float_as_uint(f);
  u += 0x7FFF + ((u >> 16) & 1);            // RNE
  return (short)(u >> 16);
}

// read-side address for the pair-row swizzle on a [R][32]-short LDS tile:
// logical (row r, 16B-group q) -> shorts offset. Stage side writes linearly
// (GLL: base + lane*16B) from a pre-swizzled global source; bijection verified:
// lane l -> (rr=l>>3, gl=(l&7)^rr, rin=2rr+(gl>>2), kq=gl&3) and this read
// maps (rin, kq) back to exactly lane*8 shorts within the slot.
__device__ __forceinline__ int swz32(int r, int q) {
  int g = ((r & 1) << 2) | q;
  return ((r >> 1) << 6) + ((g ^ ((r >> 1) & 7)) << 3);
}

// ---------------- merged prep (x->bf16 + column partials) & weight transposes ----------------
// blocks 0..127: prep (b=blk>>4, ch=blk&15). blocks 128..6783: transposes.
__device__ __forceinline__ void tc_tile(const float* __restrict__ in,
                                        short* __restrict__ outb,
                                        int R, int C, int r0, int c0,
                                        float (*t)[33], int tx, int ty) {
  #pragma unroll
  for (int i = 0; i < 4; i++)
    t[ty + 8*i][tx] = in[(size_t)(r0 + ty + 8*i) * C + c0 + tx];
  __syncthreads();
  #pragma unroll
  for (int i = 0; i < 4; i++)
    outb[(size_t)(c0 + ty + 8*i) * R + r0 + tx] = f2bf(t[tx][ty + 8*i]);
}

__global__ __launch_bounds__(256) void k_pt(
    const float* __restrict__ x, short* __restrict__ xb,
    float* __restrict__ xpart,
    const float* __restrict__ Wq, const float* __restrict__ Wk,
    const float* __restrict__ Wv, const float* __restrict__ Wo,
    short* __restrict__ Wqt, short* __restrict__ Wkt,
    short* __restrict__ Wvt, short* __restrict__ Wot) {
  __shared__ float t[32][33];
  int blk = blockIdx.x;
  if (blk < 128) {
    int b = blk >> 4, ch = blk & 15;
    const float* xp = x + ((size_t)b*SQ + (size_t)ch*64)*DM;
    short* xbp = xb + ((size_t)b*SQ + (size_t)ch*64)*DM;
    int tt = threadIdx.x;
    float a0 = 0.f, a1 = 0.f, a2 = 0.f, a3 = 0.f;
    #pragma unroll 4
    for (int r = 0; r < 64; r++) {
      float4 v = *(const float4*)&xp[(size_t)r*DM + tt*4];
      short4v s4;
      s4[0] = f2bf(v.x); s4[1] = f2bf(v.y); s4[2] = f2bf(v.z); s4[3] = f2bf(v.w);
      *(short4v*)&xbp[(size_t)r*DM + tt*4] = s4;
      a0 += v.x; a1 += v.y; a2 += v.z; a3 += v.w;
    }
    float4 o = {a0, a1, a2, a3};
    *(float4*)&xpart[((size_t)b*16 + ch)*DM + tt*4] = o;
  } else {
    int tb = blk - 128;
    int tx = threadIdx.x & 31, ty = threadIdx.x >> 5;
    if (tb < 6144) {
      int zz = tb >> 7;             // 0..47: mat*16 + head
      int within = tb & 127;
      int m = zz >> 4, hh = zz & 15;
      const float* in = (m == 0 ? Wq : m == 1 ? Wk : Wv) + (size_t)hh * DM * DKH;
      short* outb = (m == 0 ? Wqt : m == 1 ? Wkt : Wvt) + (size_t)hh * DM * DKH;
      int r0 = (within & 31) * 32;  // R=1024
      int c0 = (within >> 5) * 32;  // C=128
      tc_tile(in, outb, DM, DKH, r0, c0, t, tx, ty);
    } else {
      int w2 = tb - 6144;           // 0..511
      int r0 = (w2 & 15) * 32;      // R=512
      int c0 = (w2 >> 4) * 32;      // C=1024
      tc_tile(Wo, Wot, NA*DKH, DM, r0, c0, t, tx, ty);
    }
  }
}

// ---------------- router (parallel logits, 3 barriers) ----------------
__global__ __launch_bounds__(256) void k_router(const float* __restrict__ xpart,
                                                const float* __restrict__ Wr,
                                                const float* __restrict__ br,
                                                int* __restrict__ idxout,
                                                float* __restrict__ gatesout) {
  __shared__ float xm[DM];
  __shared__ float red[16][17];
  __shared__ float logits[NH];
  int b = blockIdx.x;
  int t = threadIdx.x;
  #pragma unroll
  for (int i = 0; i < 4; i++) {
    int d = t + 256*i;
    float s = 0.f;
    for (int c = 0; c < 16; c++) s += xpart[((size_t)b*16 + c)*DM + d];
    xm[d] = s * (1.0f/(float)SQ);
  }
  __syncthreads();
  {
    int h = t & 15, c16 = t >> 4;
    float p = 0.f;
    #pragma unroll 8
    for (int j = 0; j < 64; j++) {
      int d = c16*64 + j;
      p += xm[d] * Wr[(size_t)d*NH + h];
    }
    red[c16][h] = p;
  }
  __syncthreads();
  if (t < NH) {
    float lg = br[t];
    #pragma unroll
    for (int c = 0; c < 16; c++) lg += red[c][t];
    logits[t] = lg;
  }
  __syncthreads();
  if (t == 0) {
    float mx = logits[0];
    for (int h = 1; h < NH; h++) mx = fmaxf(mx, logits[h]);
    float e[NH], sum = 0.f;
    for (int h = 0; h < NH; h++) { e[h] = expf(logits[h]-mx); sum += e[h]; }
    float dist[NH];
    for (int h = 0; h < NH; h++) dist[h] = e[h]/sum;
    int idx[NA]; float vals[NA]; bool used[NH];
    for (int h = 0; h < NH; h++) used[h] = false;
    for (int a = 0; a < NA; a++) {
      int best = -1; float bv = -1.f;
      for (int h = 0; h < NH; h++)
        if (!used[h] && dist[h] > bv) { bv = dist[h]; best = h; }
      used[best] = true; idx[a] = best; vals[a] = bv;
    }
    float sp[NH];
    for (int h = 0; h < NH; h++) sp[h] = 0.f;
    for (int a = 0; a < NA; a++) sp[idx[a]] = vals[a];
    float m2 = sp[0];
    for (int h = 1; h < NH; h++) m2 = fmaxf(m2, sp[h]);
    float e2[NH], s2 = 0.f;
    for (int h = 0; h < NH; h++) { e2[h] = expf(sp[h]-m2); s2 += e2[h]; }
    for (int a = 0; a < NA; a++) {
      idxout[b*NA + a]   = idx[a];
      gatesout[b*NA + a] = e2[idx[a]] / s2;
    }
  }
}

// ---------------- fused QKV projection: 128x384 tile, 4-deep counted-vmcnt pipeline ----
// grid 256 = 8b*4a*8mt, blk&7 = b (XCD-L2 locality). 8 waves (2m x 4n), BK=32,
// FOUR rotating LDS buffers (128 KB), prefetch depth 3. Per K-step:
// vmcnt(8) [never drains -> 2 tiles stay in flight across the barrier],
// barrier, issue tile kt+3, ds_read+24 MFMA on tile kt. Buffer written at
// iter kt was last read at iter kt-1 -> the single barrier makes rotation safe.
__global__ __launch_bounds__(512, 2) void k_qkv(
    const short* __restrict__ xb, const short* __restrict__ Wqt,
    const short* __restrict__ Wkt, const short* __restrict__ Wvt,
    const float* __restrict__ bq, const float* __restrict__ bk,
    const float* __restrict__ bv, const int* __restrict__ idxb,
    short* __restrict__ Qo, short* __restrict__ Ko, short* __restrict__ Vto) {
  __shared__ __align__(16) short As[4][128*32];   // 4 x 8 KB
  __shared__ __align__(16) short Bs[4][384*32];   // 4 x 24 KB
  int blk = blockIdx.x;
  int b = blk & 7;
  int rest = blk >> 3;          // 0..31
  int a4 = rest & 3;
  int mt = rest >> 2;           // 0..7
  int z = b*NA + a4;
  int h = idxb[z];
  const short* Ag = xb + (size_t)b*SQ*DM + (size_t)mt*128*DM;
  int tid = threadIdx.x, lane = tid & 63, wid = tid >> 6;   // wid 0..7
  int wm = wid & 1, wn = wid >> 1;                          // 2m x 4n wave grid
  int l15 = lane & 15, quad = lane >> 4;
  // staging coords (pair-row swizzle, stage side)
  int rr8 = lane >> 3;              // 0..7
  int gl  = (lane & 7) ^ rr8;      // logical 16B-group
  int rin = rr8*2 + (gl >> 2);     // row within 16-row slot
  int kq8 = (gl & 3) * 8;          // k-offset (shorts)
  // waves 0,1 stage A (8 slots); waves 2..7 stage B (24 slots)
  const short* Wp;
  {
    int whichw = (wid - 2) >> 1;          // 0=Q,1=K,2=V (used by wid>=2)
    const short* Wbase = (whichw == 0) ? Wqt : (whichw == 1) ? Wkt : Wvt;
    Wp = Wbase + (size_t)h * (DKH * DM);
  }
  int brow = ((wid - 2) & 1) * 64;

#define STAGE_Q(T) do {                                                     \
    int bi_ = (T) & 3; int kb_ = (T)*32;                                    \
    if (wid < 2) {                                                          \
      _Pragma("unroll")                                                     \
      for (int i_ = 0; i_ < 4; i_++) {                                      \
        int s_ = wid*4 + i_;                                                \
        GLL16(Ag + (size_t)(s_*16 + rin)*DM + kb_ + kq8, &As[bi_][s_*512]); \
      }                                                                     \
    } else {                                                                \
      _Pragma("unroll")                                                     \
      for (int i_ = 0; i_ < 4; i_++) {                                      \
        GLL16(Wp + (size_t)(brow + i_*16 + rin)*DM + kb_ + kq8,             \
              &Bs[bi_][((wid-2)*4 + i_)*512]);                              \
      }                                                                     \
    }                                                                       \
  } while (0)

  f32x4 acc[4][6];
  #pragma unroll
  for (int i = 0; i < 4; i++)
    #pragma unroll
    for (int j = 0; j < 6; j++) acc[i][j] = (f32x4){0.f,0.f,0.f,0.f};

  STAGE_Q(0); STAGE_Q(1); STAGE_Q(2);     // depth-3 prologue (12 loads/thread)

  for (int kt = 0; kt < 32; kt++) {
    int buf = kt & 3;
    if (kt < 30)       asm volatile("s_waitcnt vmcnt(8)" ::: "memory");
    else if (kt == 30) asm volatile("s_waitcnt vmcnt(4)" ::: "memory");
    else               asm volatile("s_waitcnt vmcnt(0)" ::: "memory");
    __syncthreads();
    if (kt + 3 < 32) STAGE_Q(kt + 3);
    short8 a[4], bf[6];
    #pragma unroll
    for (int mi = 0; mi < 4; mi++)
      a[mi] = *(const short8*)&As[buf][swz32(wm*64 + mi*16 + l15, quad)];
    #pragma unroll
    for (int ni = 0; ni < 6; ni++)
      bf[ni] = *(const short8*)&Bs[buf][swz32(wn*96 + ni*16 + l15, quad)];
    #pragma unroll
    for (int mi = 0; mi < 4; mi++)
      #pragma unroll
      for (int ni = 0; ni < 6; ni++)
        acc[mi][ni] = MFMA16(a[mi], bf[ni], acc[mi][ni]);
  }
#undef STAGE_Q

  // epilogue: cols [0,128)=Q, [128,256)=K, [256,384)=V (transposed store)
  #pragma unroll
  for (int ni = 0; ni < 6; ni++) {
    int col = wn*96 + ni*16 + l15;
    int whichc = (wn*96 + ni*16) >> 7;   // constant per (wn,ni)
    int cl = col & 127;
    const float* bp = (whichc == 0) ? bq : (whichc == 1) ? bk : bv;
    float bcol = bp[h*DKH + cl];
    if (whichc < 2) {
      short* outp = ((whichc == 0) ? Qo : Ko) + (size_t)z*SQ*DKH;
      #pragma unroll
      for (int mi = 0; mi < 4; mi++) {
        #pragma unroll
        for (int r = 0; r < 4; r++) {
          int row = mt*128 + wm*64 + mi*16 + quad*4 + r;
          outp[(size_t)row*DKH + cl] = f2bf(acc[mi][ni][r] + bcol);
        }
      }
    } else {
      short* outp = Vto + (size_t)z*DKH*SQ;   // transposed [dkh][s]
      #pragma unroll
      for (int mi = 0; mi < 4; mi++) {
        int row0 = mt*128 + wm*64 + mi*16 + quad*4;
        short4v v;
        #pragma unroll
        for (int r = 0; r < 4; r++) v[r] = f2bf(acc[mi][ni][r] + bcol);
        *(short4v*)&outp[(size_t)cl*SQ + row0] = v;
      }
    }
  }
}

// ---------------- flash attention, bf16 MFMA, XCD-swizzled (unchanged) ----------------
__global__ __launch_bounds__(256) void k_attn(
    const short* __restrict__ Qg, const short* __restrict__ Kg,
    const short* __restrict__ Vtg, const float* __restrict__ gates,
    short* __restrict__ cat) {
  __shared__ __align__(16) short Ks[2][64*128];
  __shared__ __align__(16) short Vts[2][128*64];
  __shared__ __align__(16) short Ps[4*16*72];
  int blk = blockIdx.x;
  int slot = blk >> 3;
  int z = (blk & 7) + 8*(slot & 3);
  int qt = slot >> 2;           // 0..15
  int b = z >> 2, hs = z & 3;
  int tid = threadIdx.x, lane = tid & 63, wid = tid >> 6;
  int l15 = lane & 15, quad = lane >> 4, l7 = lane & 7, lby8 = lane >> 3;
  const short* Qp = Qg + ((size_t)z*SQ + (size_t)qt*64)*DKH;
  const short* Kp = Kg + (size_t)z*SQ*DKH;
  const short* Vp = Vtg + (size_t)z*DKH*SQ;
  short8 qa[4];
  #pragma unroll
  for (int ks = 0; ks < 4; ks++)
    qa[ks] = *(const short8*)&Qp[(size_t)(wid*16 + l15)*DKH + (ks*4 + quad)*8];
  #pragma unroll
  for (int i = 0; i < 4; i++) {
    int ci = wid*4 + i;
    int r = ci*4 + quad;
    int sc = ((l15 ^ (r & 15)) * 8);
    GLL16(Kp + (size_t)r*DKH + sc, &Ks[0][ci*512]);
    int rv = ci*8 + lby8;
    int scv = ((l7 ^ lby8) * 8);
    GLL16(Vp + (size_t)rv*SQ + scv, &Vts[0][ci*512]);
  }
  f32x4 O[8];
  #pragma unroll
  for (int dn = 0; dn < 8; dn++) O[dn] = (f32x4){0.f,0.f,0.f,0.f};
  float lsum[4] = {0.f, 0.f, 0.f, 0.f};
  const float scale = 0.08838834764831845f;   // 1/sqrt(128)
  for (int t = 0; t < 16; t++) {
    int cur = t & 1;
    asm volatile("s_waitcnt vmcnt(0)" ::: "memory");
    __syncthreads();
    if (t + 1 < 16) {
      #pragma unroll
      for (int i = 0; i < 4; i++) {
        int ci = wid*4 + i;
        int r = ci*4 + quad;
        int sc = ((l15 ^ (r & 15)) * 8);
        GLL16(Kp + (size_t)((t+1)*64 + r)*DKH + sc, &Ks[cur^1][ci*512]);
        int rv = ci*8 + lby8;
        int scv = ((l7 ^ lby8) * 8);
        GLL16(Vp + (size_t)rv*SQ + (t+1)*64 + scv, &Vts[cur^1][ci*512]);
      }
    }
    f32x4 s[4];
    #pragma unroll
    for (int nj = 0; nj < 4; nj++) s[nj] = (f32x4){0.f,0.f,0.f,0.f};
    #pragma unroll
    for (int ks = 0; ks < 4; ks++) {
      int kc = ks*4 + quad;
      #pragma unroll
      for (int nj = 0; nj < 4; nj++) {
        short8 bk8 = *(const short8*)&Ks[cur][(nj*16 + l15)*128 + ((kc ^ l15)*8)];
        s[nj] = MFMA16(qa[ks], bk8, s[nj]);
      }
    }
    #pragma unroll
    for (int r = 0; r < 4; r++) {
      float p0 = __expf(s[0][r]*scale);
      float p1 = __expf(s[1][r]*scale);
      float p2 = __expf(s[2][r]*scale);
      float p3 = __expf(s[3][r]*scale);
      lsum[r] += p0 + p1 + p2 + p3;
      int pbase = wid*1152 + (quad*4 + r)*72;
      Ps[pbase +  0 + l15] = f2bf(p0);
      Ps[pbase + 16 + l15] = f2bf(p1);
      Ps[pbase + 32 + l15] = f2bf(p2);
      Ps[pbase + 48 + l15] = f2bf(p3);
    }
    asm volatile("s_waitcnt lgkmcnt(0)" ::: "memory");
    #pragma unroll
    for (int ks2 = 0; ks2 < 2; ks2++) {
      int kc = ks2*4 + quad;
      short8 pa = *(const short8*)&Ps[wid*1152 + l15*72 + kc*8];
      #pragma unroll
      for (int dn = 0; dn < 8; dn++) {
        short8 bv8 = *(const short8*)&Vts[cur][(dn*16 + l15)*64 + ((kc ^ l7)*8)];
        O[dn] = MFMA16(pa, bv8, O[dn]);
      }
    }
  }
  float gate = gates[z];
  #pragma unroll
  for (int r = 0; r < 4; r++) {
    float rs = lsum[r];
    rs += __shfl_xor(rs, 1); rs += __shfl_xor(rs, 2);
    rs += __shfl_xor(rs, 4); rs += __shfl_xor(rs, 8);
    float sc2 = gate / rs;
    int row = qt*64 + wid*16 + quad*4 + r;
    short* cp = cat + ((size_t)(b*SQ + row))*(NA*DKH) + hs*DKH;
    #pragma unroll
    for (int dn = 0; dn < 8; dn++)
      cp[dn*16 + l15] = f2bf(O[dn][r] * sc2);
  }
}

// ---------------- output projection: 4-deep counted-vmcnt pipeline ----------------
// flat grid 512: all 8 n-tiles of an m-tile share an XCD (cat tile reuse).
// Same schedule as k_qkv: BK=32, 4 buffers (64 KB), vmcnt(8) steady state.
__global__ __launch_bounds__(256) void k_out(
    const short* __restrict__ catb, const short* __restrict__ Wot,
    const float* __restrict__ bo, float* __restrict__ out) {
  __shared__ __align__(16) short As[4][128*32];
  __shared__ __align__(16) short Bs[4][128*32];
  int blk = blockIdx.x;
  int mt = (blk & 7) + 8*(blk >> 6);   // 0..63
  int nt = (blk >> 3) & 7;             // 0..7
  const short* Ag = catb + (size_t)mt*128*(NA*DKH);
  const short* Bg = Wot + (size_t)nt*128*(NA*DKH);
  int tid = threadIdx.x, lane = tid & 63, wid = tid >> 6;  // 0..3
  int wm = wid & 1, wn = wid >> 1;
  int l15 = lane & 15, quad = lane >> 4;
  int rr8 = lane >> 3;
  int gl  = (lane & 7) ^ rr8;
  int rin = rr8*2 + (gl >> 2);
  int kq8 = (gl & 3) * 8;

#define STAGE_O(T) do {                                                       \
    int bi_ = (T) & 3; int kb_ = (T)*32;                                      \
    if (wid < 2) {                                                            \
      _Pragma("unroll")                                                       \
      for (int i_ = 0; i_ < 4; i_++) {                                        \
        int s_ = wid*4 + i_;                                                  \
        GLL16(Ag + (size_t)(s_*16 + rin)*(NA*DKH) + kb_ + kq8,                \
              &As[bi_][s_*512]);                                              \
      }                                                                       \
    } else {                                                                  \
      _Pragma("unroll")                                                       \
      for (int i_ = 0; i_ < 4; i_++) {                                        \
        int s_ = (wid-2)*4 + i_;                                              \
        GLL16(Bg + (size_t)(s_*16 + rin)*(NA*DKH) + kb_ + kq8,                \
              &Bs[bi_][s_*512]);                                              \
      }                                                                       \
    }                                                                         \
  } while (0)

  f32x4 acc[4][4];
  #pragma unroll
  for (int i = 0; i < 4; i++)
    #pragma unroll
    for (int j = 0; j < 4; j++) acc[i][j] = (f32x4){0.f,0.f,0.f,0.f};

  STAGE_O(0); STAGE_O(1); STAGE_O(2);

  for (int kt = 0; kt < 16; kt++) {
    int buf = kt & 3;
    if (kt < 14)       asm volatile("s_waitcnt vmcnt(8)" ::: "memory");
    else if (kt == 14) asm volatile("s_waitcnt vmcnt(4)" ::: "memory");
    else               asm volatile("s_waitcnt vmcnt(0)" ::: "memory");
    __syncthreads();
    if (kt + 3 < 16) STAGE_O(kt + 3);
    short8 a[4], bf[4];
    #pragma unroll
    for (int mi = 0; mi < 4; mi++)
      a[mi] = *(const short8*)&As[buf][swz32(wm*64 + mi*16 + l15, quad)];
    #pragma unroll
    for (int ni = 0; ni < 4; ni++)
      bf[ni] = *(const short8*)&Bs[buf][swz32(wn*64 + ni*16 + l15, quad)];
    #pragma unroll
    for (int mi = 0; mi < 4; mi++)
      #pragma unroll
      for (int ni = 0; ni < 4; ni++)
        acc[mi][ni] = MFMA16(a[mi], bf[ni], acc[mi][ni]);
  }
#undef STAGE_O

  #pragma unroll
  for (int mi = 0; mi < 4; mi++)
    #pragma unroll
    for (int ni = 0; ni < 4; ni++) {
      int col = nt*128 + wn*64 + ni*16 + l15;
      float bcol = bo[col];
      #pragma unroll
      for (int r = 0; r < 4; r++) {
        int row = mt*128 + wm*64 + mi*16 + quad*4 + r;
        out[(size_t)row*DM + col] = acc[mi][ni][r] + bcol;
      }
    }
}

extern "C" void kernel_launch(void* const* d_in, const int* in_sizes, int n_in,
                              void* d_out, int out_size, void* d_ws, size_t ws_size,
                              hipStream_t stream) {
  const float* x  = (const float*)d_in[0];
  const float* Wq = (const float*)d_in[1];
  const float* bq = (const float*)d_in[2];
  const float* Wk = (const float*)d_in[3];
  const float* bk = (const float*)d_in[4];
  const float* Wv = (const float*)d_in[5];
  const float* bv = (const float*)d_in[6];
  const float* Wr = (const float*)d_in[7];
  const float* br = (const float*)d_in[8];
  const float* Wo = (const float*)d_in[9];
  const float* bo = (const float*)d_in[10];
  char* ws = (char*)d_ws;
  float* xpart = (float*)(ws + WS_XPART);
  int*   idxb  = (int*)(ws + WS_IDX);
  float* gat   = (float*)(ws + WS_GATES);
  short* xb    = (short*)(ws + WS_XB);
  short* Wqt   = (short*)(ws + WS_WQT);
  short* Wkt   = (short*)(ws + WS_WKT);
  short* Wvt   = (short*)(ws + WS_WVT);
  short* Wot   = (short*)(ws + WS_WOT);
  short* Qb    = (short*)(ws + WS_Q);
  short* Kb    = (short*)(ws + WS_K);
  short* Vtb   = (short*)(ws + WS_VT);
  short* catb  = (short*)(ws + WS_CAT);
  float* out   = (float*)d_out;

  k_pt<<<6784, 256, 0, stream>>>(x, xb, xpart, Wq, Wk, Wv, Wo, Wqt, Wkt, Wvt, Wot);
  k_router<<<NB, 256, 0, stream>>>(xpart, Wr, br, idxb, gat);
  k_qkv<<<256, 512, 0, stream>>>(xb, Wqt, Wkt, Wvt, bq, bk, bv, idxb, Qb, Kb, Vtb);
  k_attn<<<512, 256, 0, stream>>>(Qb, Kb, Vtb, gat, catb);
  k_out<<<512, 256, 0, stream>>>(catb, Wot, bo, out);
}

// Round 5
// 217.168 us; speedup vs baseline: 1.0410x; 1.0410x over previous
//
#include <hip/hip_runtime.h>
#include <math.h>

#define NB 8
#define SQ 1024
#define DM 1024
#define NH 16
#define NA 4
#define DKH 128

// ---- workspace layout (byte offsets, all 128B-aligned) ----
#define WS_XPART 0
#define WS_IDX   524288
#define WS_GATES 524416
#define WS_XB    524800
#define WS_WQT   (WS_XB  + 16777216)
#define WS_WKT   (WS_WQT + 4194304)
#define WS_WVT   (WS_WKT + 4194304)
#define WS_WOT   (WS_WVT + 4194304)
#define WS_Q     (WS_WOT + 1048576)
#define WS_K     (WS_Q  + 8388608)
#define WS_VT    (WS_K  + 8388608)
#define WS_CAT   (WS_VT + 8388608)
// total = WS_CAT + 8388608 = 64,487,936 bytes

typedef __attribute__((ext_vector_type(8))) short short8;
typedef __attribute__((ext_vector_type(4))) short short4v;
typedef __attribute__((ext_vector_type(4))) float f32x4;

#define MFMA16(a, b, c) __builtin_amdgcn_mfma_f32_16x16x32_bf16(a, b, c, 0, 0, 0)
#define GLL16(g, l) __builtin_amdgcn_global_load_lds( \
    (const __attribute__((address_space(1))) void*)(g), \
    (__attribute__((address_space(3))) void*)(l), 16, 0, 0)

__device__ __forceinline__ short f2bf(float f) {
  unsigned u = __float_as_uint(f);
  u += 0x7FFF + ((u >> 16) & 1);            // RNE
  return (short)(u >> 16);
}

// ---------------- merged prep (x->bf16 + column partials) & weight transposes ----------------
// blocks 0..127: prep (b=blk>>4, ch=blk&15). blocks 128..6783: transposes.
__device__ __forceinline__ void tc_tile(const float* __restrict__ in,
                                        short* __restrict__ outb,
                                        int R, int C, int r0, int c0,
                                        float (*t)[33], int tx, int ty) {
  #pragma unroll
  for (int i = 0; i < 4; i++)
    t[ty + 8*i][tx] = in[(size_t)(r0 + ty + 8*i) * C + c0 + tx];
  __syncthreads();
  #pragma unroll
  for (int i = 0; i < 4; i++)
    outb[(size_t)(c0 + ty + 8*i) * R + r0 + tx] = f2bf(t[tx][ty + 8*i]);
}

__global__ __launch_bounds__(256) void k_pt(
    const float* __restrict__ x, short* __restrict__ xb,
    float* __restrict__ xpart,
    const float* __restrict__ Wq, const float* __restrict__ Wk,
    const float* __restrict__ Wv, const float* __restrict__ Wo,
    short* __restrict__ Wqt, short* __restrict__ Wkt,
    short* __restrict__ Wvt, short* __restrict__ Wot) {
  __shared__ float t[32][33];
  int blk = blockIdx.x;
  if (blk < 128) {
    int b = blk >> 4, ch = blk & 15;
    const float* xp = x + ((size_t)b*SQ + (size_t)ch*64)*DM;
    short* xbp = xb + ((size_t)b*SQ + (size_t)ch*64)*DM;
    int tt = threadIdx.x;
    float a0 = 0.f, a1 = 0.f, a2 = 0.f, a3 = 0.f;
    #pragma unroll 4
    for (int r = 0; r < 64; r++) {
      float4 v = *(const float4*)&xp[(size_t)r*DM + tt*4];
      short4v s4;
      s4[0] = f2bf(v.x); s4[1] = f2bf(v.y); s4[2] = f2bf(v.z); s4[3] = f2bf(v.w);
      *(short4v*)&xbp[(size_t)r*DM + tt*4] = s4;
      a0 += v.x; a1 += v.y; a2 += v.z; a3 += v.w;
    }
    float4 o = {a0, a1, a2, a3};
    *(float4*)&xpart[((size_t)b*16 + ch)*DM + tt*4] = o;
  } else {
    int tb = blk - 128;
    int tx = threadIdx.x & 31, ty = threadIdx.x >> 5;
    if (tb < 6144) {
      int zz = tb >> 7;             // 0..47: mat*16 + head
      int within = tb & 127;
      int m = zz >> 4, hh = zz & 15;
      const float* in = (m == 0 ? Wq : m == 1 ? Wk : Wv) + (size_t)hh * DM * DKH;
      short* outb = (m == 0 ? Wqt : m == 1 ? Wkt : Wvt) + (size_t)hh * DM * DKH;
      int r0 = (within & 31) * 32;  // R=1024
      int c0 = (within >> 5) * 32;  // C=128
      tc_tile(in, outb, DM, DKH, r0, c0, t, tx, ty);
    } else {
      int w2 = tb - 6144;           // 0..511
      int r0 = (w2 & 15) * 32;      // R=512
      int c0 = (w2 >> 4) * 32;      // C=1024
      tc_tile(Wo, Wot, NA*DKH, DM, r0, c0, t, tx, ty);
    }
  }
}

// ---------------- router (parallel logits, 3 barriers) ----------------
__global__ __launch_bounds__(256) void k_router(const float* __restrict__ xpart,
                                                const float* __restrict__ Wr,
                                                const float* __restrict__ br,
                                                int* __restrict__ idxout,
                                                float* __restrict__ gatesout) {
  __shared__ float xm[DM];
  __shared__ float red[16][17];
  __shared__ float logits[NH];
  int b = blockIdx.x;
  int t = threadIdx.x;
  #pragma unroll
  for (int i = 0; i < 4; i++) {
    int d = t + 256*i;
    float s = 0.f;
    for (int c = 0; c < 16; c++) s += xpart[((size_t)b*16 + c)*DM + d];
    xm[d] = s * (1.0f/(float)SQ);
  }
  __syncthreads();
  {
    int h = t & 15, c16 = t >> 4;
    float p = 0.f;
    #pragma unroll 8
    for (int j = 0; j < 64; j++) {
      int d = c16*64 + j;
      p += xm[d] * Wr[(size_t)d*NH + h];
    }
    red[c16][h] = p;
  }
  __syncthreads();
  if (t < NH) {
    float lg = br[t];
    #pragma unroll
    for (int c = 0; c < 16; c++) lg += red[c][t];
    logits[t] = lg;
  }
  __syncthreads();
  if (t == 0) {
    float mx = logits[0];
    for (int h = 1; h < NH; h++) mx = fmaxf(mx, logits[h]);
    float e[NH], sum = 0.f;
    for (int h = 0; h < NH; h++) { e[h] = expf(logits[h]-mx); sum += e[h]; }
    float dist[NH];
    for (int h = 0; h < NH; h++) dist[h] = e[h]/sum;
    int idx[NA]; float vals[NA]; bool used[NH];
    for (int h = 0; h < NH; h++) used[h] = false;
    for (int a = 0; a < NA; a++) {
      int best = -1; float bv = -1.f;
      for (int h = 0; h < NH; h++)
        if (!used[h] && dist[h] > bv) { bv = dist[h]; best = h; }
      used[best] = true; idx[a] = best; vals[a] = bv;
    }
    float sp[NH];
    for (int h = 0; h < NH; h++) sp[h] = 0.f;
    for (int a = 0; a < NA; a++) sp[idx[a]] = vals[a];
    float m2 = sp[0];
    for (int h = 1; h < NH; h++) m2 = fmaxf(m2, sp[h]);
    float e2[NH], s2 = 0.f;
    for (int h = 0; h < NH; h++) { e2[h] = expf(sp[h]-m2); s2 += e2[h]; }
    for (int a = 0; a < NA; a++) {
      idxout[b*NA + a]   = idx[a];
      gatesout[b*NA + a] = e2[idx[a]] / s2;
    }
  }
}

// ---------------- fused QKV projection: one block = 128x384 tile (Q|K|V) ----------------
// grid 256 = 8b * 4a * 8mt, blk&7 = b -> all blocks of a batch share one XCD's L2.
// 8 waves (2m x 4n, 64x96 per wave), BK=64, double-buffered LDS (128 KB),
// 2-phase schedule: vmcnt(0); barrier; stage kt+1; compute kt. A staged ONCE.
__global__ __launch_bounds__(512, 2) void k_qkv(
    const short* __restrict__ xb, const short* __restrict__ Wqt,
    const short* __restrict__ Wkt, const short* __restrict__ Wvt,
    const float* __restrict__ bq, const float* __restrict__ bk,
    const float* __restrict__ bv, const int* __restrict__ idxb,
    short* __restrict__ Qo, short* __restrict__ Ko, short* __restrict__ Vto) {
  __shared__ __align__(16) short As[2][128*64];   // 2 x 16 KB
  __shared__ __align__(16) short Bs[2][384*64];   // 2 x 48 KB
  int blk = blockIdx.x;
  int b = blk & 7;
  int rest = blk >> 3;          // 0..31
  int a4 = rest & 3;
  int mt = rest >> 2;           // 0..7
  int z = b*NA + a4;
  int h = idxb[z];
  const short* Ag = xb + (size_t)b*SQ*DM + (size_t)mt*128*DM;
  int tid = threadIdx.x, lane = tid & 63, wid = tid >> 6;   // wid 0..7
  int wm = wid & 1, wn = wid >> 1;                          // 2m x 4n wave grid
  int l15 = lane & 15, quad = lane >> 4, l7 = lane & 7, srow = lane >> 3;
  int scol = (l7 ^ srow) * 8;   // source-side XOR swizzle (LDS dest stays linear)
  const short* Wp;
  {
    int whichw = (wid - 2) >> 1;          // 0=Q, 1=K, 2=V (only used by wid>=2)
    const short* Wbase = (whichw == 0) ? Wqt : (whichw == 1) ? Wkt : Wvt;
    Wp = Wbase + (size_t)h * (DKH * DM);
  }
  int brow_base = ((wid - 2) & 1) * 64;

#define STAGE_QKV(KT, AS, BS) do {                                          \
    if (wid < 2) {                                                          \
      _Pragma("unroll")                                                     \
      for (int i_ = 0; i_ < 8; i_++) {                                      \
        int slot_ = wid*8 + i_;                                             \
        GLL16(Ag + (size_t)(slot_*8 + srow)*DM + (KT)*64 + scol,            \
              (AS) + slot_*512);                                            \
      }                                                                     \
    } else {                                                                \
      _Pragma("unroll")                                                     \
      for (int i_ = 0; i_ < 8; i_++) {                                      \
        int bslot_ = (wid-2)*8 + i_;                                        \
        GLL16(Wp + (size_t)(brow_base + i_*8 + srow)*DM + (KT)*64 + scol,   \
              (BS) + bslot_*512);                                           \
      }                                                                     \
    }                                                                       \
  } while (0)

  f32x4 acc[4][6];
  #pragma unroll
  for (int i = 0; i < 4; i++)
    #pragma unroll
    for (int j = 0; j < 6; j++) acc[i][j] = (f32x4){0.f,0.f,0.f,0.f};

  STAGE_QKV(0, &As[0][0], &Bs[0][0]);

  for (int kt = 0; kt < 16; kt++) {
    int cur = kt & 1;
    asm volatile("s_waitcnt vmcnt(0)" ::: "memory");
    __syncthreads();
    if (kt + 1 < 16)
      STAGE_QKV(kt + 1, &As[cur ^ 1][0], &Bs[cur ^ 1][0]);
    #pragma unroll
    for (int ks = 0; ks < 2; ks++) {
      int kc = ks*4 + quad;
      short8 a[4], bf[6];
      #pragma unroll
      for (int mi = 0; mi < 4; mi++)
        a[mi] = *(const short8*)&As[cur][(wm*64 + mi*16 + l15)*64 + ((kc ^ l7)*8)];
      #pragma unroll
      for (int ni = 0; ni < 6; ni++)
        bf[ni] = *(const short8*)&Bs[cur][(wn*96 + ni*16 + l15)*64 + ((kc ^ l7)*8)];
      #pragma unroll
      for (int mi = 0; mi < 4; mi++)
        #pragma unroll
        for (int ni = 0; ni < 6; ni++)
          acc[mi][ni] = MFMA16(a[mi], bf[ni], acc[mi][ni]);
    }
  }
#undef STAGE_QKV

  // epilogue: cols [0,128)=Q, [128,256)=K, [256,384)=V (transposed store)
  #pragma unroll
  for (int ni = 0; ni < 6; ni++) {
    int col = wn*96 + ni*16 + l15;
    int whichc = (wn*96 + ni*16) >> 7;   // constant per (wn,ni)
    int cl = col & 127;
    const float* bp = (whichc == 0) ? bq : (whichc == 1) ? bk : bv;
    float bcol = bp[h*DKH + cl];
    if (whichc < 2) {
      short* outp = ((whichc == 0) ? Qo : Ko) + (size_t)z*SQ*DKH;
      #pragma unroll
      for (int mi = 0; mi < 4; mi++) {
        #pragma unroll
        for (int r = 0; r < 4; r++) {
          int row = mt*128 + wm*64 + mi*16 + quad*4 + r;
          outp[(size_t)row*DKH + cl] = f2bf(acc[mi][ni][r] + bcol);
        }
      }
    } else {
      short* outp = Vto + (size_t)z*DKH*SQ;   // transposed [dkh][s]
      #pragma unroll
      for (int mi = 0; mi < 4; mi++) {
        int row0 = mt*128 + wm*64 + mi*16 + quad*4;
        short4v v;
        #pragma unroll
        for (int r = 0; r < 4; r++) v[r] = f2bf(acc[mi][ni][r] + bcol);
        *(short4v*)&outp[(size_t)cl*SQ + row0] = v;
      }
    }
  }
}

// ---------------- flash attention: split K/V waits + setprio ----------------
// flat grid 512: xcd lane = z&7 (4 z per XCD -> 2 MB K/V set fits 4 MB L2).
// K-loads issued first, V-loads second; top-of-loop vmcnt(4) releases QK^T as
// soon as K lands (V still in flight through softmax); second vmcnt+barrier
// covers V before PV while K(t+1) prefetch stays in flight. Never a full
// drain in steady state. setprio(1) wraps both MFMA clusters (T5, m191).
__global__ __launch_bounds__(256) void k_attn(
    const short* __restrict__ Qg, const short* __restrict__ Kg,
    const short* __restrict__ Vtg, const float* __restrict__ gates,
    short* __restrict__ cat) {
  __shared__ __align__(16) short Ks[2][64*128];
  __shared__ __align__(16) short Vts[2][128*64];
  __shared__ __align__(16) short Ps[4*16*72];
  int blk = blockIdx.x;
  int slot = blk >> 3;
  int z = (blk & 7) + 8*(slot & 3);
  int qt = slot >> 2;           // 0..15
  int b = z >> 2, hs = z & 3;
  int tid = threadIdx.x, lane = tid & 63, wid = tid >> 6;
  int l15 = lane & 15, quad = lane >> 4, l7 = lane & 7, lby8 = lane >> 3;
  const short* Qp = Qg + ((size_t)z*SQ + (size_t)qt*64)*DKH;
  const short* Kp = Kg + (size_t)z*SQ*DKH;
  const short* Vp = Vtg + (size_t)z*DKH*SQ;
  short8 qa[4];
  #pragma unroll
  for (int ks = 0; ks < 4; ks++)
    qa[ks] = *(const short8*)&Qp[(size_t)(wid*16 + l15)*DKH + (ks*4 + quad)*8];
  // prologue: K loads first, then V loads (issue order matters for vmcnt)
  #pragma unroll
  for (int i = 0; i < 4; i++) {
    int ci = wid*4 + i;
    int r = ci*4 + quad;
    int sc = ((l15 ^ (r & 15)) * 8);
    GLL16(Kp + (size_t)r*DKH + sc, &Ks[0][ci*512]);
  }
  #pragma unroll
  for (int i = 0; i < 4; i++) {
    int ci = wid*4 + i;
    int rv = ci*8 + lby8;
    int scv = ((l7 ^ lby8) * 8);
    GLL16(Vp + (size_t)rv*SQ + scv, &Vts[0][ci*512]);
  }
  f32x4 O[8];
  #pragma unroll
  for (int dn = 0; dn < 8; dn++) O[dn] = (f32x4){0.f,0.f,0.f,0.f};
  float lsum[4] = {0.f, 0.f, 0.f, 0.f};
  const float scale = 0.08838834764831845f;   // 1/sqrt(128)
  for (int t = 0; t < 16; t++) {
    int cur = t & 1;
    // ---- wait K(t) only; V(t) stays in flight ----
    asm volatile("s_waitcnt vmcnt(4)" ::: "memory");
    __syncthreads();
    if (t + 1 < 16) {   // prefetch K(t+1); buffer cur^1 last read at step t-1
      #pragma unroll
      for (int i = 0; i < 4; i++) {
        int ci = wid*4 + i;
        int r = ci*4 + quad;
        int sc = ((l15 ^ (r & 15)) * 8);
        GLL16(Kp + (size_t)((t+1)*64 + r)*DKH + sc, &Ks[cur^1][ci*512]);
      }
    }
    f32x4 s[4];
    #pragma unroll
    for (int nj = 0; nj < 4; nj++) s[nj] = (f32x4){0.f,0.f,0.f,0.f};
    __builtin_amdgcn_s_setprio(1);
    #pragma unroll
    for (int ks = 0; ks < 4; ks++) {
      int kc = ks*4 + quad;
      #pragma unroll
      for (int nj = 0; nj < 4; nj++) {
        short8 bk8 = *(const short8*)&Ks[cur][(nj*16 + l15)*128 + ((kc ^ l15)*8)];
        s[nj] = MFMA16(qa[ks], bk8, s[nj]);
      }
    }
    __builtin_amdgcn_s_setprio(0);
    #pragma unroll
    for (int r = 0; r < 4; r++) {
      float p0 = __expf(s[0][r]*scale);
      float p1 = __expf(s[1][r]*scale);
      float p2 = __expf(s[2][r]*scale);
      float p3 = __expf(s[3][r]*scale);
      lsum[r] += p0 + p1 + p2 + p3;
      int pbase = wid*1152 + (quad*4 + r)*72;
      Ps[pbase +  0 + l15] = f2bf(p0);
      Ps[pbase + 16 + l15] = f2bf(p1);
      Ps[pbase + 32 + l15] = f2bf(p2);
      Ps[pbase + 48 + l15] = f2bf(p3);
    }
    // ---- wait V(t); K(t+1) (if any) stays in flight ----
    if (t + 1 < 16) asm volatile("s_waitcnt vmcnt(4)" ::: "memory");
    else            asm volatile("s_waitcnt vmcnt(0)" ::: "memory");
    __syncthreads();
    if (t + 1 < 16) {   // prefetch V(t+1); buffer cur^1 last read at step t-1
      #pragma unroll
      for (int i = 0; i < 4; i++) {
        int ci = wid*4 + i;
        int rv = ci*8 + lby8;
        int scv = ((l7 ^ lby8) * 8);
        GLL16(Vp + (size_t)rv*SQ + (t+1)*64 + scv, &Vts[cur^1][ci*512]);
      }
    }
    asm volatile("s_waitcnt lgkmcnt(0)" ::: "memory");
    __builtin_amdgcn_s_setprio(1);
    #pragma unroll
    for (int ks2 = 0; ks2 < 2; ks2++) {
      int kc = ks2*4 + quad;
      short8 pa = *(const short8*)&Ps[wid*1152 + l15*72 + kc*8];
      #pragma unroll
      for (int dn = 0; dn < 8; dn++) {
        short8 bv8 = *(const short8*)&Vts[cur][(dn*16 + l15)*64 + ((kc ^ l7)*8)];
        O[dn] = MFMA16(pa, bv8, O[dn]);
      }
    }
    __builtin_amdgcn_s_setprio(0);
  }
  float gate = gates[z];
  #pragma unroll
  for (int r = 0; r < 4; r++) {
    float rs = lsum[r];
    rs += __shfl_xor(rs, 1); rs += __shfl_xor(rs, 2);
    rs += __shfl_xor(rs, 4); rs += __shfl_xor(rs, 8);
    float sc2 = gate / rs;
    int row = qt*64 + wid*16 + quad*4 + r;
    short* cp = cat + ((size_t)(b*SQ + row))*(NA*DKH) + hs*DKH;
    #pragma unroll
    for (int dn = 0; dn < 8; dn++)
      cp[dn*16 + l15] = f2bf(O[dn][r] * sc2);
  }
}

// ---------------- output projection: bf16 MFMA GEMM, XCD-swizzled ----------------
// flat grid 512: all 8 n-tiles of an m-tile share an XCD (cat tile reuse).
__global__ __launch_bounds__(256) void k_out(
    const short* __restrict__ catb, const short* __restrict__ Wot,
    const float* __restrict__ bo, float* __restrict__ out) {
  __shared__ __align__(16) short As[2][128*64];
  __shared__ __align__(16) short Bs[2][128*64];
  int blk = blockIdx.x;
  int mt = (blk & 7) + 8*(blk >> 6);   // 0..63
  int nt = (blk >> 3) & 7;             // 0..7
  const short* Ag = catb + (size_t)mt*128*(NA*DKH);
  const short* Bg = Wot + (size_t)nt*128*(NA*DKH);
  int tid = threadIdx.x, lane = tid & 63, wid = tid >> 6;
  int wm = wid & 1, wn = wid >> 1;
  int l15 = lane & 15, quad = lane >> 4, l7 = lane & 7, lby8 = lane >> 3;
  int srow = lby8;
  int scol = ((l7 ^ lby8) * 8);
  f32x4 acc[4][4];
  #pragma unroll
  for (int i = 0; i < 4; i++)
    #pragma unroll
    for (int j = 0; j < 4; j++) acc[i][j] = (f32x4){0.f,0.f,0.f,0.f};
  #pragma unroll
  for (int i = 0; i < 4; i++) {
    int ci = wid*4 + i;
    GLL16(Ag + (size_t)(ci*8 + srow)*(NA*DKH) + scol, &As[0][ci*512]);
    GLL16(Bg + (size_t)(ci*8 + srow)*(NA*DKH) + scol, &Bs[0][ci*512]);
  }
  for (int kt = 0; kt < 8; kt++) {
    int cur = kt & 1;
    asm volatile("s_waitcnt vmcnt(0)" ::: "memory");
    __syncthreads();
    if (kt + 1 < 8) {
      #pragma unroll
      for (int i = 0; i < 4; i++) {
        int ci = wid*4 + i;
        GLL16(Ag + (size_t)(ci*8 + srow)*(NA*DKH) + (kt+1)*64 + scol, &As[cur^1][ci*512]);
        GLL16(Bg + (size_t)(ci*8 + srow)*(NA*DKH) + (kt+1)*64 + scol, &Bs[cur^1][ci*512]);
      }
    }
    #pragma unroll
    for (int ks = 0; ks < 2; ks++) {
      int kc = ks*4 + quad;
      short8 a[4], bf[4];
      #pragma unroll
      for (int mi = 0; mi < 4; mi++)
        a[mi] = *(const short8*)&As[cur][(wm*64 + mi*16 + l15)*64 + ((kc ^ l7)*8)];
      #pragma unroll
      for (int ni = 0; ni < 4; ni++)
        bf[ni] = *(const short8*)&Bs[cur][(wn*64 + ni*16 + l15)*64 + ((kc ^ l7)*8)];
      #pragma unroll
      for (int mi = 0; mi < 4; mi++)
        #pragma unroll
        for (int ni = 0; ni < 4; ni++)
          acc[mi][ni] = MFMA16(a[mi], bf[ni], acc[mi][ni]);
    }
  }
  #pragma unroll
  for (int mi = 0; mi < 4; mi++)
    #pragma unroll
    for (int ni = 0; ni < 4; ni++) {
      int col = nt*128 + wn*64 + ni*16 + l15;
      float bcol = bo[col];
      #pragma unroll
      for (int r = 0; r < 4; r++) {
        int row = mt*128 + wm*64 + mi*16 + quad*4 + r;
        out[(size_t)row*DM + col] = acc[mi][ni][r] + bcol;
      }
    }
}

extern "C" void kernel_launch(void* const* d_in, const int* in_sizes, int n_in,
                              void* d_out, int out_size, void* d_ws, size_t ws_size,
                              hipStream_t stream) {
  const float* x  = (const float*)d_in[0];
  const float* Wq = (const float*)d_in[1];
  const float* bq = (const float*)d_in[2];
  const float* Wk = (const float*)d_in[3];
  const float* bk = (const float*)d_in[4];
  const float* Wv = (const float*)d_in[5];
  const float* bv = (const float*)d_in[6];
  const float* Wr = (const float*)d_in[7];
  const float* br = (const float*)d_in[8];
  const float* Wo = (const float*)d_in[9];
  const float* bo = (const float*)d_in[10];
  char* ws = (char*)d_ws;
  float* xpart = (float*)(ws + WS_XPART);
  int*   idxb  = (int*)(ws + WS_IDX);
  float* gat   = (float*)(ws + WS_GATES);
  short* xb    = (short*)(ws + WS_XB);
  short* Wqt   = (short*)(ws + WS_WQT);
  short* Wkt   = (short*)(ws + WS_WKT);
  short* Wvt   = (short*)(ws + WS_WVT);
  short* Wot   = (short*)(ws + WS_WOT);
  short* Qb    = (short*)(ws + WS_Q);
  short* Kb    = (short*)(ws + WS_K);
  short* Vtb   = (short*)(ws + WS_VT);
  short* catb  = (short*)(ws + WS_CAT);
  float* out   = (float*)d_out;

  k_pt<<<6784, 256, 0, stream>>>(x, xb, xpart, Wq, Wk, Wv, Wo, Wqt, Wkt, Wvt, Wot);
  k_router<<<NB, 256, 0, stream>>>(xpart, Wr, br, idxb, gat);
  k_qkv<<<256, 512, 0, stream>>>(xb, Wqt, Wkt, Wvt, bq, bk, bv, idxb, Qb, Kb, Vtb);
  k_attn<<<512, 256, 0, stream>>>(Qb, Kb, Vtb, gat, catb);
  k_out<<<512, 256, 0, stream>>>(catb, Wot, bo, out);
}

// Round 6
// 216.296 us; speedup vs baseline: 1.0452x; 1.0040x over previous
//
#include <hip/hip_runtime.h>
#include <math.h>

#define NB 8
#define SQ 1024
#define DM 1024
#define NH 16
#define NA 4
#define DKH 128

// ---- workspace layout (byte offsets, all 128B-aligned) ----
#define WS_XPART 0
#define WS_IDX   524288
#define WS_GATES 524416
#define WS_XB    524800
#define WS_WQT   (WS_XB  + 16777216)
#define WS_WKT   (WS_WQT + 4194304)
#define WS_WVT   (WS_WKT + 4194304)
#define WS_WOT   (WS_WVT + 4194304)
#define WS_Q     (WS_WOT + 1048576)
#define WS_K     (WS_Q  + 8388608)
#define WS_VT    (WS_K  + 8388608)
#define WS_CAT   (WS_VT + 8388608)
// total = WS_CAT + 8388608 = 64,487,936 bytes

typedef __attribute__((ext_vector_type(8))) short short8;
typedef __attribute__((ext_vector_type(4))) short short4v;
typedef __attribute__((ext_vector_type(4))) float f32x4;

#define MFMA16(a, b, c) __builtin_amdgcn_mfma_f32_16x16x32_bf16(a, b, c, 0, 0, 0)
#define GLL16(g, l) __builtin_amdgcn_global_load_lds( \
    (const __attribute__((address_space(1))) void*)(g), \
    (__attribute__((address_space(3))) void*)(l), 16, 0, 0)
#define SBAR() __builtin_amdgcn_s_barrier()

__device__ __forceinline__ short f2bf(float f) {
  unsigned u = __float_as_uint(f);
  u += 0x7FFF + ((u >> 16) & 1);            // RNE
  return (short)(u >> 16);
}

// ---------------- merged prep (x->bf16 + column partials) & weight transposes ----------------
// blocks 0..127: prep (b=blk>>4, ch=blk&15). blocks 128..6783: transposes.
__device__ __forceinline__ void tc_tile(const float* __restrict__ in,
                                        short* __restrict__ outb,
                                        int R, int C, int r0, int c0,
                                        float (*t)[33], int tx, int ty) {
  #pragma unroll
  for (int i = 0; i < 4; i++)
    t[ty + 8*i][tx] = in[(size_t)(r0 + ty + 8*i) * C + c0 + tx];
  __syncthreads();
  #pragma unroll
  for (int i = 0; i < 4; i++)
    outb[(size_t)(c0 + ty + 8*i) * R + r0 + tx] = f2bf(t[tx][ty + 8*i]);
}

__global__ __launch_bounds__(256) void k_pt(
    const float* __restrict__ x, short* __restrict__ xb,
    float* __restrict__ xpart,
    const float* __restrict__ Wq, const float* __restrict__ Wk,
    const float* __restrict__ Wv, const float* __restrict__ Wo,
    short* __restrict__ Wqt, short* __restrict__ Wkt,
    short* __restrict__ Wvt, short* __restrict__ Wot) {
  __shared__ float t[32][33];
  int blk = blockIdx.x;
  if (blk < 128) {
    int b = blk >> 4, ch = blk & 15;
    const float* xp = x + ((size_t)b*SQ + (size_t)ch*64)*DM;
    short* xbp = xb + ((size_t)b*SQ + (size_t)ch*64)*DM;
    int tt = threadIdx.x;
    float a0 = 0.f, a1 = 0.f, a2 = 0.f, a3 = 0.f;
    #pragma unroll 4
    for (int r = 0; r < 64; r++) {
      float4 v = *(const float4*)&xp[(size_t)r*DM + tt*4];
      short4v s4;
      s4[0] = f2bf(v.x); s4[1] = f2bf(v.y); s4[2] = f2bf(v.z); s4[3] = f2bf(v.w);
      *(short4v*)&xbp[(size_t)r*DM + tt*4] = s4;
      a0 += v.x; a1 += v.y; a2 += v.z; a3 += v.w;
    }
    float4 o = {a0, a1, a2, a3};
    *(float4*)&xpart[((size_t)b*16 + ch)*DM + tt*4] = o;
  } else {
    int tb = blk - 128;
    int tx = threadIdx.x & 31, ty = threadIdx.x >> 5;
    if (tb < 6144) {
      int zz = tb >> 7;             // 0..47: mat*16 + head
      int within = tb & 127;
      int m = zz >> 4, hh = zz & 15;
      const float* in = (m == 0 ? Wq : m == 1 ? Wk : Wv) + (size_t)hh * DM * DKH;
      short* outb = (m == 0 ? Wqt : m == 1 ? Wkt : Wvt) + (size_t)hh * DM * DKH;
      int r0 = (within & 31) * 32;  // R=1024
      int c0 = (within >> 5) * 32;  // C=128
      tc_tile(in, outb, DM, DKH, r0, c0, t, tx, ty);
    } else {
      int w2 = tb - 6144;           // 0..511
      int r0 = (w2 & 15) * 32;      // R=512
      int c0 = (w2 >> 4) * 32;      // C=1024
      tc_tile(Wo, Wot, NA*DKH, DM, r0, c0, t, tx, ty);
    }
  }
}

// ---------------- router (parallel logits, 3 barriers) ----------------
__global__ __launch_bounds__(256) void k_router(const float* __restrict__ xpart,
                                                const float* __restrict__ Wr,
                                                const float* __restrict__ br,
                                                int* __restrict__ idxout,
                                                float* __restrict__ gatesout) {
  __shared__ float xm[DM];
  __shared__ float red[16][17];
  __shared__ float logits[NH];
  int b = blockIdx.x;
  int t = threadIdx.x;
  #pragma unroll
  for (int i = 0; i < 4; i++) {
    int d = t + 256*i;
    float s = 0.f;
    for (int c = 0; c < 16; c++) s += xpart[((size_t)b*16 + c)*DM + d];
    xm[d] = s * (1.0f/(float)SQ);
  }
  __syncthreads();
  {
    int h = t & 15, c16 = t >> 4;
    float p = 0.f;
    #pragma unroll 8
    for (int j = 0; j < 64; j++) {
      int d = c16*64 + j;
      p += xm[d] * Wr[(size_t)d*NH + h];
    }
    red[c16][h] = p;
  }
  __syncthreads();
  if (t < NH) {
    float lg = br[t];
    #pragma unroll
    for (int c = 0; c < 16; c++) lg += red[c][t];
    logits[t] = lg;
  }
  __syncthreads();
  if (t == 0) {
    float mx = logits[0];
    for (int h = 1; h < NH; h++) mx = fmaxf(mx, logits[h]);
    float e[NH], sum = 0.f;
    for (int h = 0; h < NH; h++) { e[h] = expf(logits[h]-mx); sum += e[h]; }
    float dist[NH];
    for (int h = 0; h < NH; h++) dist[h] = e[h]/sum;
    int idx[NA]; float vals[NA]; bool used[NH];
    for (int h = 0; h < NH; h++) used[h] = false;
    for (int a = 0; a < NA; a++) {
      int best = -1; float bv = -1.f;
      for (int h = 0; h < NH; h++)
        if (!used[h] && dist[h] > bv) { bv = dist[h]; best = h; }
      used[best] = true; idx[a] = best; vals[a] = bv;
    }
    float sp[NH];
    for (int h = 0; h < NH; h++) sp[h] = 0.f;
    for (int a = 0; a < NA; a++) sp[idx[a]] = vals[a];
    float m2 = sp[0];
    for (int h = 1; h < NH; h++) m2 = fmaxf(m2, sp[h]);
    float e2[NH], s2 = 0.f;
    for (int h = 0; h < NH; h++) { e2[h] = expf(sp[h]-m2); s2 += e2[h]; }
    for (int a = 0; a < NA; a++) {
      idxout[b*NA + a]   = idx[a];
      gatesout[b*NA + a] = e2[idx[a]] / s2;
    }
  }
}

// ---------------- fused QKV projection: counted-vmcnt pipeline, raw barriers -------------
// grid 256 = 8b*4a*8mt, blk&7 = b (XCD-L2 locality). 8 waves (2m x 4n), BK=64,
// dbuf LDS (128 KB). Per iter: vmcnt(8) [tile kt landed; kt+1's 8 loads STAY in
// flight across the barrier], s_barrier, compute buf[kt&1], s_barrier, stage
// kt+2 into buf[kt&1]. Raw s_barrier (NOT __syncthreads) so the compiler does
// not insert a vmcnt(0) drain — the round-5 post-mortem's key finding.
// Safety: every wave issues 8 loads of every stage and waits its own before
// barrier #1 -> cross-wave LDS consistency; barrier #2 orders all reads of
// buf[cur] before its re-stage (ds_reads complete: their MFMAs forced lgkm waits).
__global__ __launch_bounds__(512, 2) void k_qkv(
    const short* __restrict__ xb, const short* __restrict__ Wqt,
    const short* __restrict__ Wkt, const short* __restrict__ Wvt,
    const float* __restrict__ bq, const float* __restrict__ bk,
    const float* __restrict__ bv, const int* __restrict__ idxb,
    short* __restrict__ Qo, short* __restrict__ Ko, short* __restrict__ Vto) {
  __shared__ __align__(16) short As[2][128*64];   // 2 x 16 KB
  __shared__ __align__(16) short Bs[2][384*64];   // 2 x 48 KB
  int blk = blockIdx.x;
  int b = blk & 7;
  int rest = blk >> 3;          // 0..31
  int a4 = rest & 3;
  int mt = rest >> 2;           // 0..7
  int z = b*NA + a4;
  int h = idxb[z];
  const short* Ag = xb + (size_t)b*SQ*DM + (size_t)mt*128*DM;
  int tid = threadIdx.x, lane = tid & 63, wid = tid >> 6;   // wid 0..7
  int wm = wid & 1, wn = wid >> 1;                          // 2m x 4n wave grid
  int l15 = lane & 15, quad = lane >> 4, l7 = lane & 7, srow = lane >> 3;
  int scol = (l7 ^ srow) * 8;   // source-side XOR swizzle (LDS dest stays linear)
  const short* Wp;
  {
    int whichw = (wid - 2) >> 1;          // 0=Q, 1=K, 2=V (only used by wid>=2)
    const short* Wbase = (whichw == 0) ? Wqt : (whichw == 1) ? Wkt : Wvt;
    Wp = Wbase + (size_t)h * (DKH * DM);
  }
  int brow_base = ((wid - 2) & 1) * 64;

#define STAGE_QKV(KT, AS, BS) do {                                          \
    if (wid < 2) {                                                          \
      _Pragma("unroll")                                                     \
      for (int i_ = 0; i_ < 8; i_++) {                                      \
        int slot_ = wid*8 + i_;                                             \
        GLL16(Ag + (size_t)(slot_*8 + srow)*DM + (KT)*64 + scol,            \
              (AS) + slot_*512);                                            \
      }                                                                     \
    } else {                                                                \
      _Pragma("unroll")                                                     \
      for (int i_ = 0; i_ < 8; i_++) {                                      \
        int bslot_ = (wid-2)*8 + i_;                                        \
        GLL16(Wp + (size_t)(brow_base + i_*8 + srow)*DM + (KT)*64 + scol,   \
              (BS) + bslot_*512);                                           \
      }                                                                     \
    }                                                                       \
  } while (0)

  f32x4 acc[4][6];
  #pragma unroll
  for (int i = 0; i < 4; i++)
    #pragma unroll
    for (int j = 0; j < 6; j++) acc[i][j] = (f32x4){0.f,0.f,0.f,0.f};

  STAGE_QKV(0, &As[0][0], &Bs[0][0]);
  STAGE_QKV(1, &As[1][0], &Bs[1][0]);

  for (int kt = 0; kt < 16; kt++) {
    int cur = kt & 1;
    if (kt < 15) asm volatile("s_waitcnt vmcnt(8)" ::: "memory");
    else         asm volatile("s_waitcnt vmcnt(0)" ::: "memory");
    SBAR();
    #pragma unroll
    for (int ks = 0; ks < 2; ks++) {
      int kc = ks*4 + quad;
      short8 a[4], bf[6];
      #pragma unroll
      for (int mi = 0; mi < 4; mi++)
        a[mi] = *(const short8*)&As[cur][(wm*64 + mi*16 + l15)*64 + ((kc ^ l7)*8)];
      #pragma unroll
      for (int ni = 0; ni < 6; ni++)
        bf[ni] = *(const short8*)&Bs[cur][(wn*96 + ni*16 + l15)*64 + ((kc ^ l7)*8)];
      #pragma unroll
      for (int mi = 0; mi < 4; mi++)
        #pragma unroll
        for (int ni = 0; ni < 6; ni++)
          acc[mi][ni] = MFMA16(a[mi], bf[ni], acc[mi][ni]);
    }
    SBAR();
    if (kt + 2 < 16)
      STAGE_QKV(kt + 2, &As[cur][0], &Bs[cur][0]);
  }
#undef STAGE_QKV

  // epilogue: cols [0,128)=Q, [128,256)=K, [256,384)=V (transposed store)
  #pragma unroll
  for (int ni = 0; ni < 6; ni++) {
    int col = wn*96 + ni*16 + l15;
    int whichc = (wn*96 + ni*16) >> 7;   // constant per (wn,ni)
    int cl = col & 127;
    const float* bp = (whichc == 0) ? bq : (whichc == 1) ? bk : bv;
    float bcol = bp[h*DKH + cl];
    if (whichc < 2) {
      short* outp = ((whichc == 0) ? Qo : Ko) + (size_t)z*SQ*DKH;
      #pragma unroll
      for (int mi = 0; mi < 4; mi++) {
        #pragma unroll
        for (int r = 0; r < 4; r++) {
          int row = mt*128 + wm*64 + mi*16 + quad*4 + r;
          outp[(size_t)row*DKH + cl] = f2bf(acc[mi][ni][r] + bcol);
        }
      }
    } else {
      short* outp = Vto + (size_t)z*DKH*SQ;   // transposed [dkh][s]
      #pragma unroll
      for (int mi = 0; mi < 4; mi++) {
        int row0 = mt*128 + wm*64 + mi*16 + quad*4;
        short4v v;
        #pragma unroll
        for (int r = 0; r < 4; r++) v[r] = f2bf(acc[mi][ni][r] + bcol);
        *(short4v*)&outp[(size_t)cl*SQ + row0] = v;
      }
    }
  }
}

// ---------------- flash attention: split K/V waits + setprio + raw barriers ----------------
// flat grid 512: xcd lane = z&7 (4 z per XCD -> 2 MB K/V set fits 4 MB L2).
// With raw s_barrier the split waits now actually keep loads in flight:
// vmcnt(4) at top releases QK^T as soon as K lands (V flying through softmax);
// second vmcnt(4)+barrier covers V while K(t+1) stays in flight.
__global__ __launch_bounds__(256) void k_attn(
    const short* __restrict__ Qg, const short* __restrict__ Kg,
    const short* __restrict__ Vtg, const float* __restrict__ gates,
    short* __restrict__ cat) {
  __shared__ __align__(16) short Ks[2][64*128];
  __shared__ __align__(16) short Vts[2][128*64];
  __shared__ __align__(16) short Ps[4*16*72];
  int blk = blockIdx.x;
  int slot = blk >> 3;
  int z = (blk & 7) + 8*(slot & 3);
  int qt = slot >> 2;           // 0..15
  int b = z >> 2, hs = z & 3;
  int tid = threadIdx.x, lane = tid & 63, wid = tid >> 6;
  int l15 = lane & 15, quad = lane >> 4, l7 = lane & 7, lby8 = lane >> 3;
  const short* Qp = Qg + ((size_t)z*SQ + (size_t)qt*64)*DKH;
  const short* Kp = Kg + (size_t)z*SQ*DKH;
  const short* Vp = Vtg + (size_t)z*DKH*SQ;
  short8 qa[4];
  #pragma unroll
  for (int ks = 0; ks < 4; ks++)
    qa[ks] = *(const short8*)&Qp[(size_t)(wid*16 + l15)*DKH + (ks*4 + quad)*8];
  // prologue: K loads first, then V loads (issue order matters for vmcnt)
  #pragma unroll
  for (int i = 0; i < 4; i++) {
    int ci = wid*4 + i;
    int r = ci*4 + quad;
    int sc = ((l15 ^ (r & 15)) * 8);
    GLL16(Kp + (size_t)r*DKH + sc, &Ks[0][ci*512]);
  }
  #pragma unroll
  for (int i = 0; i < 4; i++) {
    int ci = wid*4 + i;
    int rv = ci*8 + lby8;
    int scv = ((l7 ^ lby8) * 8);
    GLL16(Vp + (size_t)rv*SQ + scv, &Vts[0][ci*512]);
  }
  f32x4 O[8];
  #pragma unroll
  for (int dn = 0; dn < 8; dn++) O[dn] = (f32x4){0.f,0.f,0.f,0.f};
  float lsum[4] = {0.f, 0.f, 0.f, 0.f};
  const float scale = 0.08838834764831845f;   // 1/sqrt(128)
  for (int t = 0; t < 16; t++) {
    int cur = t & 1;
    // ---- wait K(t) only; V(t) stays in flight ----
    asm volatile("s_waitcnt vmcnt(4)" ::: "memory");
    SBAR();
    if (t + 1 < 16) {   // prefetch K(t+1); buffer cur^1 last read at step t-1
      #pragma unroll
      for (int i = 0; i < 4; i++) {
        int ci = wid*4 + i;
        int r = ci*4 + quad;
        int sc = ((l15 ^ (r & 15)) * 8);
        GLL16(Kp + (size_t)((t+1)*64 + r)*DKH + sc, &Ks[cur^1][ci*512]);
      }
    }
    f32x4 s[4];
    #pragma unroll
    for (int nj = 0; nj < 4; nj++) s[nj] = (f32x4){0.f,0.f,0.f,0.f};
    __builtin_amdgcn_s_setprio(1);
    #pragma unroll
    for (int ks = 0; ks < 4; ks++) {
      int kc = ks*4 + quad;
      #pragma unroll
      for (int nj = 0; nj < 4; nj++) {
        short8 bk8 = *(const short8*)&Ks[cur][(nj*16 + l15)*128 + ((kc ^ l15)*8)];
        s[nj] = MFMA16(qa[ks], bk8, s[nj]);
      }
    }
    __builtin_amdgcn_s_setprio(0);
    #pragma unroll
    for (int r = 0; r < 4; r++) {
      float p0 = __expf(s[0][r]*scale);
      float p1 = __expf(s[1][r]*scale);
      float p2 = __expf(s[2][r]*scale);
      float p3 = __expf(s[3][r]*scale);
      lsum[r] += p0 + p1 + p2 + p3;
      int pbase = wid*1152 + (quad*4 + r)*72;
      Ps[pbase +  0 + l15] = f2bf(p0);
      Ps[pbase + 16 + l15] = f2bf(p1);
      Ps[pbase + 32 + l15] = f2bf(p2);
      Ps[pbase + 48 + l15] = f2bf(p3);
    }
    // ---- wait V(t); K(t+1) (if any) stays in flight ----
    if (t + 1 < 16) asm volatile("s_waitcnt vmcnt(4)" ::: "memory");
    else            asm volatile("s_waitcnt vmcnt(0)" ::: "memory");
    SBAR();
    if (t + 1 < 16) {   // prefetch V(t+1); buffer cur^1 last read at step t-1
      #pragma unroll
      for (int i = 0; i < 4; i++) {
        int ci = wid*4 + i;
        int rv = ci*8 + lby8;
        int scv = ((l7 ^ lby8) * 8);
        GLL16(Vp + (size_t)rv*SQ + (t+1)*64 + scv, &Vts[cur^1][ci*512]);
      }
    }
    asm volatile("s_waitcnt lgkmcnt(0)" ::: "memory");
    __builtin_amdgcn_s_setprio(1);
    #pragma unroll
    for (int ks2 = 0; ks2 < 2; ks2++) {
      int kc = ks2*4 + quad;
      short8 pa = *(const short8*)&Ps[wid*1152 + l15*72 + kc*8];
      #pragma unroll
      for (int dn = 0; dn < 8; dn++) {
        short8 bv8 = *(const short8*)&Vts[cur][(dn*16 + l15)*64 + ((kc ^ l7)*8)];
        O[dn] = MFMA16(pa, bv8, O[dn]);
      }
    }
    __builtin_amdgcn_s_setprio(0);
  }
  float gate = gates[z];
  #pragma unroll
  for (int r = 0; r < 4; r++) {
    float rs = lsum[r];
    rs += __shfl_xor(rs, 1); rs += __shfl_xor(rs, 2);
    rs += __shfl_xor(rs, 4); rs += __shfl_xor(rs, 8);
    float sc2 = gate / rs;
    int row = qt*64 + wid*16 + quad*4 + r;
    short* cp = cat + ((size_t)(b*SQ + row))*(NA*DKH) + hs*DKH;
    #pragma unroll
    for (int dn = 0; dn < 8; dn++)
      cp[dn*16 + l15] = f2bf(O[dn][r] * sc2);
  }
}

// ---------------- output projection: counted-vmcnt pipeline, raw barriers ----------------
// flat grid 512: all 8 n-tiles of an m-tile share an XCD (cat tile reuse).
// Same schedule as k_qkv: stage t0,t1; per iter vmcnt(8)/bar/compute/bar/stage(kt+2).
__global__ __launch_bounds__(256) void k_out(
    const short* __restrict__ catb, const short* __restrict__ Wot,
    const float* __restrict__ bo, float* __restrict__ out) {
  __shared__ __align__(16) short As[2][128*64];
  __shared__ __align__(16) short Bs[2][128*64];
  int blk = blockIdx.x;
  int mt = (blk & 7) + 8*(blk >> 6);   // 0..63
  int nt = (blk >> 3) & 7;             // 0..7
  const short* Ag = catb + (size_t)mt*128*(NA*DKH);
  const short* Bg = Wot + (size_t)nt*128*(NA*DKH);
  int tid = threadIdx.x, lane = tid & 63, wid = tid >> 6;
  int wm = wid & 1, wn = wid >> 1;
  int l15 = lane & 15, quad = lane >> 4, l7 = lane & 7, lby8 = lane >> 3;
  int srow = lby8;
  int scol = ((l7 ^ lby8) * 8);

#define STAGE_O(KT, AS, BS) do {                                            \
    _Pragma("unroll")                                                       \
    for (int i_ = 0; i_ < 4; i_++) {                                        \
      int ci_ = wid*4 + i_;                                                 \
      GLL16(Ag + (size_t)(ci_*8 + srow)*(NA*DKH) + (KT)*64 + scol,          \
            (AS) + ci_*512);                                                \
      GLL16(Bg + (size_t)(ci_*8 + srow)*(NA*DKH) + (KT)*64 + scol,          \
            (BS) + ci_*512);                                                \
    }                                                                       \
  } while (0)

  f32x4 acc[4][4];
  #pragma unroll
  for (int i = 0; i < 4; i++)
    #pragma unroll
    for (int j = 0; j < 4; j++) acc[i][j] = (f32x4){0.f,0.f,0.f,0.f};

  STAGE_O(0, &As[0][0], &Bs[0][0]);
  STAGE_O(1, &As[1][0], &Bs[1][0]);

  for (int kt = 0; kt < 8; kt++) {
    int cur = kt & 1;
    if (kt < 7) asm volatile("s_waitcnt vmcnt(8)" ::: "memory");
    else        asm volatile("s_waitcnt vmcnt(0)" ::: "memory");
    SBAR();
    #pragma unroll
    for (int ks = 0; ks < 2; ks++) {
      int kc = ks*4 + quad;
      short8 a[4], bf[4];
      #pragma unroll
      for (int mi = 0; mi < 4; mi++)
        a[mi] = *(const short8*)&As[cur][(wm*64 + mi*16 + l15)*64 + ((kc ^ l7)*8)];
      #pragma unroll
      for (int ni = 0; ni < 4; ni++)
        bf[ni] = *(const short8*)&Bs[cur][(wn*64 + ni*16 + l15)*64 + ((kc ^ l7)*8)];
      #pragma unroll
      for (int mi = 0; mi < 4; mi++)
        #pragma unroll
        for (int ni = 0; ni < 4; ni++)
          acc[mi][ni] = MFMA16(a[mi], bf[ni], acc[mi][ni]);
    }
    SBAR();
    if (kt + 2 < 8)
      STAGE_O(kt + 2, &As[cur][0], &Bs[cur][0]);
  }
#undef STAGE_O

  #pragma unroll
  for (int mi = 0; mi < 4; mi++)
    #pragma unroll
    for (int ni = 0; ni < 4; ni++) {
      int col = nt*128 + wn*64 + ni*16 + l15;
      float bcol = bo[col];
      #pragma unroll
      for (int r = 0; r < 4; r++) {
        int row = mt*128 + wm*64 + mi*16 + quad*4 + r;
        out[(size_t)row*DM + col] = acc[mi][ni][r] + bcol;
      }
    }
}

extern "C" void kernel_launch(void* const* d_in, const int* in_sizes, int n_in,
                              void* d_out, int out_size, void* d_ws, size_t ws_size,
                              hipStream_t stream) {
  const float* x  = (const float*)d_in[0];
  const float* Wq = (const float*)d_in[1];
  const float* bq = (const float*)d_in[2];
  const float* Wk = (const float*)d_in[3];
  const float* bk = (const float*)d_in[4];
  const float* Wv = (const float*)d_in[5];
  const float* bv = (const float*)d_in[6];
  const float* Wr = (const float*)d_in[7];
  const float* br = (const float*)d_in[8];
  const float* Wo = (const float*)d_in[9];
  const float* bo = (const float*)d_in[10];
  char* ws = (char*)d_ws;
  float* xpart = (float*)(ws + WS_XPART);
  int*   idxb  = (int*)(ws + WS_IDX);
  float* gat   = (float*)(ws + WS_GATES);
  short* xb    = (short*)(ws + WS_XB);
  short* Wqt   = (short*)(ws + WS_WQT);
  short* Wkt   = (short*)(ws + WS_WKT);
  short* Wvt   = (short*)(ws + WS_WVT);
  short* Wot   = (short*)(ws + WS_WOT);
  short* Qb    = (short*)(ws + WS_Q);
  short* Kb    = (short*)(ws + WS_K);
  short* Vtb   = (short*)(ws + WS_VT);
  short* catb  = (short*)(ws + WS_CAT);
  float* out   = (float*)d_out;

  k_pt<<<6784, 256, 0, stream>>>(x, xb, xpart, Wq, Wk, Wv, Wo, Wqt, Wkt, Wvt, Wot);
  k_router<<<NB, 256, 0, stream>>>(xpart, Wr, br, idxb, gat);
  k_qkv<<<256, 512, 0, stream>>>(xb, Wqt, Wkt, Wvt, bq, bk, bv, idxb, Qb, Kb, Vtb);
  k_attn<<<512, 256, 0, stream>>>(Qb, Kb, Vtb, gat, catb);
  k_out<<<512, 256, 0, stream>>>(catb, Wot, bo, out);
}